// Round 3
// baseline (9771.540 us; speedup 1.0000x reference)
//
#include <hip/hip_runtime.h>
#include <hip/hip_bf16.h>
#include <cstdint>
#include <cstddef>

#define D 256
#define RNUM 8
#define LAYERS 3

// GEMM tile: 64 rows x 256 cols per block, K-panels of 16, 8x8 per thread
#define BM 64
#define BN 256
#define BK 16
#define TM 8
#define TN 8

// ---------------------------------------------------------------------------
// ws layout (bytes):
//   [0]    int flag
//   [4]    int counts[8]   (zeroed by zero_meta_kernel)
//   [36]   int cursor[8]   (zeroed by zero_meta_kernel)
//   [68]   int offsets[9]
//   [104]  int tileoff[9]
//   [256]  int src32[E], dst32[E], rel32[E], perm[E]      (4.8 MB)
//   [al.]  float h1[N*D]                                  (51.2 MB)
// total ≈ 56 MB
// ---------------------------------------------------------------------------

__global__ void zero_meta_kernel(int* __restrict__ meta) {
    if (threadIdx.x < 16) meta[threadIdx.x] = 0;   // counts[8] + cursor[8]
}

__global__ void detect_kernel(const int* __restrict__ ei32, int* __restrict__ flag) {
    __shared__ int allzero;
    if (threadIdx.x == 0) allzero = 1;
    __syncthreads();
    // int64 node ids < 2^31 have all-zero high words -> every odd int32 is 0.
    if (ei32[2 * threadIdx.x + 1] != 0) allzero = 0;  // benign race: all writers write 0
    __syncthreads();
    if (threadIdx.x == 0) flag[0] = allzero;
}

__global__ void convert_count_kernel(const void* __restrict__ ei,
                                     const void* __restrict__ et,
                                     const int* __restrict__ flag,
                                     int* __restrict__ src32, int* __restrict__ dst32,
                                     int* __restrict__ rel32, int* __restrict__ counts,
                                     int E, int N) {
    int e = blockIdx.x * blockDim.x + threadIdx.x;
    if (e >= E) return;
    int s, d, r;
    if (flag[0]) {
        const long long* ei64 = (const long long*)ei;
        const long long* et64 = (const long long*)et;
        s = (int)ei64[e];
        d = (int)ei64[E + e];
        r = (int)et64[e];
    } else {
        const int* eii = (const int*)ei;
        const int* eti = (const int*)et;
        s = eii[e];
        d = eii[E + e];
        r = eti[e];
    }
    // defensive clamps: wrong values -> wrong answer (diagnosable), never a fault
    if ((unsigned)s >= (unsigned)N) s = 0;
    if ((unsigned)d >= (unsigned)N) d = 0;
    if ((unsigned)r >= (unsigned)RNUM) r = 0;
    src32[e] = s;
    dst32[e] = d;
    rel32[e] = r;
    atomicAdd(&counts[r], 1);
}

__global__ void prefix_kernel(const int* __restrict__ counts,
                              int* __restrict__ offsets, int* __restrict__ tileoff) {
    if (threadIdx.x != 0 || blockIdx.x != 0) return;
    int o = 0, t = 0;
    for (int r = 0; r < RNUM; ++r) {
        offsets[r] = o;
        tileoff[r] = t;
        o += counts[r];
        t += (counts[r] + BM - 1) / BM;
    }
    offsets[RNUM] = o;
    tileoff[RNUM] = t;
}

__global__ void fill_kernel(const int* __restrict__ rel32,
                            int* __restrict__ cursor, const int* __restrict__ offsets,
                            int* __restrict__ perm, int E) {
    int e = blockIdx.x * blockDim.x + threadIdx.x;
    if (e >= E) return;
    int r = rel32[e];
    int pos = atomicAdd(&cursor[r], 1);
    int slot = offsets[r] + pos;
    if ((unsigned)slot < (unsigned)E) perm[slot] = e;
}

// ---------------------------------------------------------------------------
// MODE 0: hout[row] = hin[row] @ B0 + bias           (dense rows, plain store)
// MODE 1: hout[dst[e]] += hin[src[e]] @ W[rel]       (gathered edges, atomicAdd)
// ---------------------------------------------------------------------------
template <int MODE>
__global__ __launch_bounds__(256, 2)
void rgemm_kernel(const float* __restrict__ hin,
                  const float* __restrict__ B0,    // root (MODE0) or W base (MODE1)
                  const float* __restrict__ bias,  // MODE0 only
                  float* __restrict__ hout,
                  const int* __restrict__ src32, const int* __restrict__ dst32,
                  const int* __restrict__ perm,
                  const int* __restrict__ offsets, const int* __restrict__ tileoff,
                  int N, int E) {
    __shared__ float As[BK][BM + 4];   // [k][m]
    __shared__ float Bs[BK][BN + 4];   // [k][n]

    const int tid = threadIdx.x;

    int row0 = 0, base_slot = 0, cnt_tile = BM;
    const float* Bmat = B0;
    if (MODE == 0) {
        row0 = blockIdx.x * BM;
    } else {
        const int t = blockIdx.x;
        if (t >= tileoff[RNUM]) return;   // uniform early-exit, before any barrier
        int r = 0;
        while (t >= tileoff[r + 1]) ++r;
        const int lt = t - tileoff[r];
        const int off = offsets[r];
        const int cnt = offsets[r + 1] - off;
        base_slot = off + lt * BM;
        const int rem = off + cnt - base_slot;       // edges left from this tile start
        cnt_tile = rem < BM ? rem : BM;              // valid rows in THIS tile
        Bmat = B0 + (size_t)r * D * D;
    }

    // A loader: thread -> (m, k-quad)
    const int la_m = tid >> 2;            // 0..63
    const int la_k = (tid & 3) * 4;       // 0,4,8,12
    const float* aptr;
    if (MODE == 0) {
        int row = row0 + la_m;
        if (row >= N) row = N - 1;        // clamped; writeback is guarded
        aptr = hin + (size_t)row * D;
    } else {
        const int lm = (la_m < cnt_tile) ? la_m : 0;   // clamped; writeback guarded
        int e = perm[base_slot + lm];
        if ((unsigned)e >= (unsigned)E) e = 0;          // defensive
        aptr = hin + (size_t)src32[e] * D;
    }

    // compute coords: 32 col-groups x 8 row-groups
    const int n0 = (tid & 31) * TN;
    const int m0 = (tid >> 5) * TM;

    float acc[TM][TN];
#pragma unroll
    for (int i = 0; i < TM; ++i)
#pragma unroll
        for (int j = 0; j < TN; ++j) acc[i][j] = 0.f;

#pragma unroll 1
    for (int kt = 0; kt < D / BK; ++kt) {
        const float4 av = *reinterpret_cast<const float4*>(aptr + kt * BK + la_k);
        float4 bv[4];
#pragma unroll
        for (int i = 0; i < 4; ++i) {
            const int f = tid + 256 * i;      // 0..1023
            const int k = f >> 6;             // 0..15
            const int n4 = (f & 63) * 4;      // 0..252
            bv[i] = *reinterpret_cast<const float4*>(Bmat + (size_t)(kt * BK + k) * D + n4);
        }
        __syncthreads();   // previous iteration's LDS reads complete
        As[la_k + 0][la_m] = av.x;
        As[la_k + 1][la_m] = av.y;
        As[la_k + 2][la_m] = av.z;
        As[la_k + 3][la_m] = av.w;
#pragma unroll
        for (int i = 0; i < 4; ++i) {
            const int f = tid + 256 * i;
            const int k = f >> 6;
            const int n4 = (f & 63) * 4;
            *reinterpret_cast<float4*>(&Bs[k][n4]) = bv[i];
        }
        __syncthreads();
#pragma unroll
        for (int kk = 0; kk < BK; ++kk) {
            float a[TM], b[TN];
            const float4 a0 = *reinterpret_cast<const float4*>(&As[kk][m0]);
            const float4 a1 = *reinterpret_cast<const float4*>(&As[kk][m0 + 4]);
            a[0] = a0.x; a[1] = a0.y; a[2] = a0.z; a[3] = a0.w;
            a[4] = a1.x; a[5] = a1.y; a[6] = a1.z; a[7] = a1.w;
            const float4 b0 = *reinterpret_cast<const float4*>(&Bs[kk][n0]);
            const float4 b1 = *reinterpret_cast<const float4*>(&Bs[kk][n0 + 4]);
            b[0] = b0.x; b[1] = b0.y; b[2] = b0.z; b[3] = b0.w;
            b[4] = b1.x; b[5] = b1.y; b[6] = b1.z; b[7] = b1.w;
#pragma unroll
            for (int i = 0; i < TM; ++i)
#pragma unroll
                for (int j = 0; j < TN; ++j)
                    acc[i][j] = fmaf(a[i], b[j], acc[i][j]);
        }
    }

    if (MODE == 0) {
        const float4 bb0 = *reinterpret_cast<const float4*>(bias + n0);
        const float4 bb1 = *reinterpret_cast<const float4*>(bias + n0 + 4);
        const float bb[TN] = {bb0.x, bb0.y, bb0.z, bb0.w, bb1.x, bb1.y, bb1.z, bb1.w};
#pragma unroll
        for (int i = 0; i < TM; ++i) {
            const int row = row0 + m0 + i;
            if (row < N) {
                float4 o0, o1;
                o0.x = acc[i][0] + bb[0]; o0.y = acc[i][1] + bb[1];
                o0.z = acc[i][2] + bb[2]; o0.w = acc[i][3] + bb[3];
                o1.x = acc[i][4] + bb[4]; o1.y = acc[i][5] + bb[5];
                o1.z = acc[i][6] + bb[6]; o1.w = acc[i][7] + bb[7];
                float* p = hout + (size_t)row * D + n0;
                *reinterpret_cast<float4*>(p) = o0;
                *reinterpret_cast<float4*>(p + 4) = o1;
            }
        }
    } else {
#pragma unroll
        for (int i = 0; i < TM; ++i) {
            const int lm = m0 + i;
            if (lm < cnt_tile) {
                int e = perm[base_slot + lm];
                if ((unsigned)e >= (unsigned)E) e = 0;   // defensive
                float* p = hout + (size_t)dst32[e] * D + n0;
#pragma unroll
                for (int j = 0; j < TN; ++j)
                    atomicAdd(p + j, acc[i][j]);
            }
        }
    }
}

// ---------------------------------------------------------------------------
template <int SIG>  // 0 = relu, 1 = sigmoid
__global__ __launch_bounds__(256)
void act_kernel(float4* __restrict__ h, int n4) {
    const int i = blockIdx.x * blockDim.x + threadIdx.x;
    if (i >= n4) return;
    float4 v = h[i];
    if (SIG == 0) {
        v.x = fmaxf(v.x, 0.f); v.y = fmaxf(v.y, 0.f);
        v.z = fmaxf(v.z, 0.f); v.w = fmaxf(v.w, 0.f);
    } else {
        v.x = 1.f / (1.f + __expf(-v.x));
        v.y = 1.f / (1.f + __expf(-v.y));
        v.z = 1.f / (1.f + __expf(-v.z));
        v.w = 1.f / (1.f + __expf(-v.w));
    }
    h[i] = v;
}

// ---------------------------------------------------------------------------
extern "C" void kernel_launch(void* const* d_in, const int* in_sizes, int n_in,
                              void* d_out, int out_size, void* d_ws, size_t ws_size,
                              hipStream_t stream) {
    const float* x       = (const float*)d_in[0];
    const float* weights = (const float*)d_in[1];   // [L, R, D, D]
    const float* roots   = (const float*)d_in[2];   // [L, D, D]
    const float* biases  = (const float*)d_in[3];   // [L, D]
    const void*  ei      = d_in[4];                 // [2, E] int32 or int64
    const void*  et      = d_in[5];                 // [E]

    const int N = in_sizes[0] / D;    // 50000
    const int E = in_sizes[4] / 2;    // 300000

    char* ws = (char*)d_ws;
    int* flag    = (int*)(ws + 0);
    int* counts  = (int*)(ws + 4);
    int* offsets = (int*)(ws + 68);
    int* tileoff = (int*)(ws + 104);
    int* src32   = (int*)(ws + 256);
    int* dst32   = src32 + E;
    int* rel32   = dst32 + E;
    int* perm    = rel32 + E;
    size_t hoff = (256 + (size_t)4 * E * 4 + 255) & ~(size_t)255;
    float* h1 = (float*)(ws + hoff);

    // --- edge preprocessing (same every call; inputs are static) ---
    zero_meta_kernel<<<1, 64, 0, stream>>>(counts);   // counts[8] + cursor[8]
    detect_kernel<<<1, 256, 0, stream>>>((const int*)ei, flag);
    const int eb = (E + 255) / 256;
    convert_count_kernel<<<eb, 256, 0, stream>>>(ei, et, flag, src32, dst32, rel32,
                                                 counts, E, N);
    prefix_kernel<<<1, 1, 0, stream>>>(counts, offsets, tileoff);
    fill_kernel<<<eb, 256, 0, stream>>>(rel32, counts + 8 /*cursor*/, offsets, perm, E);

    const int denseTiles = (N + BM - 1) / BM;            // 782
    const int maxEdgeTiles = (E + BM - 1) / BM + RNUM;   // >= sum of per-rel tiles
    const int actBlocks = (N * (D / 4) + 255) / 256;

    const float* hin = x;
    for (int l = 0; l < LAYERS; ++l) {
        // ping-pong: l0 -> d_out, l1 -> h1, l2 -> d_out
        float* hout = (l == 1) ? h1 : (float*)d_out;
        const float* Wl = weights + (size_t)l * RNUM * D * D;
        const float* rl = roots + (size_t)l * D * D;
        const float* bl = biases + (size_t)l * D;

        rgemm_kernel<0><<<denseTiles, 256, 0, stream>>>(
            hin, rl, bl, hout, src32, dst32, perm, offsets, tileoff, N, E);
        rgemm_kernel<1><<<maxEdgeTiles, 256, 0, stream>>>(
            hin, Wl, nullptr, hout, src32, dst32, perm, offsets, tileoff, N, E);
        if (l == LAYERS - 1)
            act_kernel<1><<<actBlocks, 256, 0, stream>>>((float4*)hout, N * (D / 4));
        else
            act_kernel<0><<<actBlocks, 256, 0, stream>>>((float4*)hout, N * (D / 4));
        hin = hout;
    }
}

// Round 4
// 5886.770 us; speedup vs baseline: 1.6599x; 1.6599x over previous
//
#include <hip/hip_runtime.h>
#include <cstdint>
#include <cstddef>

#define D 256
#define RNUM 8
#define LAYERS 3
#define BM 32          // dst rows per block tile
#define BK 16          // K panel
#define AST 264        // LDS row stride (floats): 256 + 8 pad

// ---------------------------------------------------------------------------
// ws layout (bytes):
//   [0]     int flag                     (1 = int64 indices, 0 = int32)
//   [256]   int pp[N*8+1]                counts -> in-place exclusive scan (CSR)
//   [..]    int cur[N*8]                 fill cursors (zeroed)
//   [..]    int bsum[512]                scan block sums
//   [..]    int esrc[E]                  src node of each edge, sorted by (dst,rel)
//   [align] float h1[N*D]                layer-1 activations
//   total ~= 55.6 MB (same footprint as the round-3 version that passed)
// ---------------------------------------------------------------------------

__global__ void zero_kernel(int* __restrict__ p, int n) {
    int i = blockIdx.x * blockDim.x + threadIdx.x;
    if (i < n) p[i] = 0;
}

__global__ void detect_kernel(const int* __restrict__ ei32, int* __restrict__ flag) {
    __shared__ int allzero;
    if (threadIdx.x == 0) allzero = 1;
    __syncthreads();
    // int64 node ids < 2^31 have all-zero high dwords -> every odd int32 is 0
    if (ei32[2 * threadIdx.x + 1] != 0) allzero = 0;  // benign race: all write 0
    __syncthreads();
    if (threadIdx.x == 0) flag[0] = allzero;
}

__device__ __forceinline__ void load_edge(const void* ei, const void* et, int flg,
                                          int e, int E, int N,
                                          int& s, int& d, int& r) {
    if (flg) {
        const long long* a = (const long long*)ei;
        const long long* b = (const long long*)et;
        s = (int)a[e]; d = (int)a[E + e]; r = (int)b[e];
    } else {
        const int* a = (const int*)ei;
        const int* b = (const int*)et;
        s = a[e]; d = a[E + e]; r = b[e];
    }
    if ((unsigned)s >= (unsigned)N) s = 0;       // defensive: wrong answer, never a fault
    if ((unsigned)d >= (unsigned)N) d = 0;
    if ((unsigned)r >= (unsigned)RNUM) r = 0;
}

__global__ void count_kernel(const void* __restrict__ ei, const void* __restrict__ et,
                             const int* __restrict__ flag, int* __restrict__ pp,
                             int E, int N) {
    int e = blockIdx.x * blockDim.x + threadIdx.x;
    if (e >= E) return;
    int s, d, r;
    load_edge(ei, et, flag[0], e, E, N, s, d, r);
    atomicAdd(&pp[d * RNUM + r], 1);
}

__global__ void scan_blocks_kernel(int* __restrict__ pp, int* __restrict__ bsum, int n) {
    __shared__ int sb[1024];
    const int t = threadIdx.x;
    const int i = blockIdx.x * 1024 + t;
    const int v = (i < n) ? pp[i] : 0;
    sb[t] = v;
    __syncthreads();
    for (int off = 1; off < 1024; off <<= 1) {
        int x = 0;
        if (t >= off) x = sb[t - off];
        __syncthreads();
        if (t >= off) sb[t] += x;
        __syncthreads();
    }
    if (i < n) pp[i] = sb[t] - v;             // exclusive within block
    if (t == 1023) bsum[blockIdx.x] = sb[t];  // block total
}

__global__ void scan_sums_kernel(int* __restrict__ bsum, int nb) {
    __shared__ int sb[512];
    const int t = threadIdx.x;
    const int v = (t < nb) ? bsum[t] : 0;
    sb[t] = v;
    __syncthreads();
    for (int off = 1; off < 512; off <<= 1) {
        int x = 0;
        if (t >= off) x = sb[t - off];
        __syncthreads();
        if (t >= off) sb[t] += x;
        __syncthreads();
    }
    if (t < nb) bsum[t] = sb[t] - v;          // exclusive block offsets
}

__global__ void scan_add_kernel(int* __restrict__ pp, const int* __restrict__ bsum,
                                int n, int E) {
    const int i = blockIdx.x * 1024 + threadIdx.x;
    if (i < n) pp[i] += bsum[blockIdx.x];
    if (i == 0) pp[n] = E;                    // total (all edges counted exactly once)
}

__global__ void fill_kernel(const void* __restrict__ ei, const void* __restrict__ et,
                            const int* __restrict__ flag, const int* __restrict__ pp,
                            int* __restrict__ cur, int* __restrict__ esrc,
                            int E, int N) {
    int e = blockIdx.x * blockDim.x + threadIdx.x;
    if (e >= E) return;
    int s, d, r;
    load_edge(ei, et, flag[0], e, E, N, s, d, r);
    const int key = d * RNUM + r;
    const int pos = atomicAdd(&cur[key], 1);
    const int slot = pp[key] + pos;
    if ((unsigned)slot < (unsigned)E) esrc[slot] = s;
}

// ---------------------------------------------------------------------------
// Fused RGCN layer: per 32-row dst tile, for each segment (root + 8 rels):
//   gather/sum A rows into LDS agg tile, then masked 32x256 GEMM panel.
// Output rows written exactly once (bias + activation fused). No atomics.
// ---------------------------------------------------------------------------
template <int ACT>  // 0 = relu, 1 = sigmoid
__global__ __launch_bounds__(256, 3)
void layer_kernel(const float* __restrict__ hin,   // [N, D]
                  const float* __restrict__ W,     // [R, D, D]
                  const float* __restrict__ root,  // [D, D]
                  const float* __restrict__ bias,  // [D]
                  const int* __restrict__ pp,      // [N*8 + 1] CSR
                  const int* __restrict__ esrc,    // [E] src sorted by (dst,rel)
                  float* __restrict__ hout,        // [N, D]
                  int N) {
    __shared__ float aggA[BM * AST];   // A tile, [m][k] layout (broadcast reads)
    __shared__ float Bs[BK * AST];     // B panel, [k][n]

    const int tid = threadIdx.x;
    const int row_base = blockIdx.x * BM;
    const int w = tid >> 6;            // wave id (0..3)
    const int l = tid & 63;            // lane
    const int m0 = (tid >> 5) * 4;     // this thread's 4-row group
    const int n0 = (tid & 31) * 8;     // this thread's 8 output cols

    float acc[4][8];
#pragma unroll
    for (int i = 0; i < 4; ++i)
#pragma unroll
        for (int j = 0; j < 8; ++j) acc[i][j] = 0.f;

    for (int seg = 0; seg <= RNUM; ++seg) {
        const float* Bmat = (seg == 0) ? root : (W + (size_t)(seg - 1) * D * D);

        __syncthreads();   // previous segment's FMA reads of aggA complete

        // ---- stage A rows into LDS (wave w owns rows w, w+4, ..., w+28)
        if (seg == 0) {
            for (int m = w; m < BM; m += 4) {
                int r = row_base + m;
                if (r >= N) r = N - 1;   // clamp; those rows masked at store
                const float4 v = *reinterpret_cast<const float4*>(
                    hin + (size_t)r * D + l * 4);
                *reinterpret_cast<float4*>(&aggA[m * AST + l * 4]) = v;
            }
        } else {
            const int rel = seg - 1;
            for (int m = w; m < BM; m += 4) {
                const int r = row_base + m;
                if (r < N) {
                    const int p = r * RNUM + rel;
                    const int beg = pp[p];
                    const int end = pp[p + 1];
                    if (end > beg) {
                        float sx = 0.f, sy = 0.f, sz = 0.f, sw = 0.f;
                        for (int j = beg; j < end; ++j) {
                            const int s = esrc[j];
                            const float4 v = *reinterpret_cast<const float4*>(
                                hin + (size_t)s * D + l * 4);
                            sx += v.x; sy += v.y; sz += v.z; sw += v.w;
                        }
                        float4 o; o.x = sx; o.y = sy; o.z = sz; o.w = sw;
                        *reinterpret_cast<float4*>(&aggA[m * AST + l * 4]) = o;
                    }
                    // empty rows: stale LDS data, but masked out of the FMA loop
                }
            }
        }

        // ---- per-thread nonempty mask for its 4 rows
        int mask;
        if (seg == 0) {
            mask = 0xF;
        } else {
            mask = 0;
            const int rel = seg - 1;
#pragma unroll
            for (int i = 0; i < 4; ++i) {
                const int r = row_base + m0 + i;
                if (r < N) {
                    const int p = r * RNUM + rel;
                    if (pp[p + 1] > pp[p]) mask |= (1 << i);
                }
            }
        }

        __syncthreads();   // agg tile visible to all

        // ---- GEMM over K = 256 in panels of BK
        for (int kt = 0; kt < D / BK; ++kt) {
            float4 bv[4];
#pragma unroll
            for (int q = 0; q < 4; ++q) {       // prefetch before barrier
                const int idx = tid + 256 * q;
                const int k = idx >> 6, n4 = (idx & 63) * 4;
                bv[q] = *reinterpret_cast<const float4*>(
                    Bmat + (size_t)(kt * BK + k) * D + n4);
            }
            __syncthreads();   // previous panel's Bs reads complete
#pragma unroll
            for (int q = 0; q < 4; ++q) {
                const int idx = tid + 256 * q;
                const int k = idx >> 6, n4 = (idx & 63) * 4;
                *reinterpret_cast<float4*>(&Bs[k * AST + n4]) = bv[q];
            }
            __syncthreads();
#pragma unroll
            for (int kk = 0; kk < BK; ++kk) {
                const float4 b0 = *reinterpret_cast<const float4*>(&Bs[kk * AST + n0]);
                const float4 b1 = *reinterpret_cast<const float4*>(&Bs[kk * AST + n0 + 4]);
#pragma unroll
                for (int i = 0; i < 4; ++i) {
                    if (mask & (1 << i)) {
                        const float a = aggA[(m0 + i) * AST + kt * BK + kk];  // broadcast
                        acc[i][0] = fmaf(a, b0.x, acc[i][0]);
                        acc[i][1] = fmaf(a, b0.y, acc[i][1]);
                        acc[i][2] = fmaf(a, b0.z, acc[i][2]);
                        acc[i][3] = fmaf(a, b0.w, acc[i][3]);
                        acc[i][4] = fmaf(a, b1.x, acc[i][4]);
                        acc[i][5] = fmaf(a, b1.y, acc[i][5]);
                        acc[i][6] = fmaf(a, b1.z, acc[i][6]);
                        acc[i][7] = fmaf(a, b1.w, acc[i][7]);
                    }
                }
            }
        }
    }

    // ---- epilogue: bias + activation, single store per output row
    const float4 bb0 = *reinterpret_cast<const float4*>(bias + n0);
    const float4 bb1 = *reinterpret_cast<const float4*>(bias + n0 + 4);
    const float bb[8] = {bb0.x, bb0.y, bb0.z, bb0.w, bb1.x, bb1.y, bb1.z, bb1.w};
#pragma unroll
    for (int i = 0; i < 4; ++i) {
        const int r = row_base + m0 + i;
        if (r < N) {
            float v[8];
#pragma unroll
            for (int j = 0; j < 8; ++j) {
                const float z = acc[i][j] + bb[j];
                v[j] = (ACT == 0) ? fmaxf(z, 0.f) : 1.f / (1.f + __expf(-z));
            }
            float4 o0, o1;
            o0.x = v[0]; o0.y = v[1]; o0.z = v[2]; o0.w = v[3];
            o1.x = v[4]; o1.y = v[5]; o1.z = v[6]; o1.w = v[7];
            float* p = hout + (size_t)r * D + n0;
            *reinterpret_cast<float4*>(p) = o0;
            *reinterpret_cast<float4*>(p + 4) = o1;
        }
    }
}

// ---------------------------------------------------------------------------
extern "C" void kernel_launch(void* const* d_in, const int* in_sizes, int n_in,
                              void* d_out, int out_size, void* d_ws, size_t ws_size,
                              hipStream_t stream) {
    const float* x       = (const float*)d_in[0];
    const float* weights = (const float*)d_in[1];   // [L, R, D, D]
    const float* roots   = (const float*)d_in[2];   // [L, D, D]
    const float* biases  = (const float*)d_in[3];   // [L, D]
    const void*  ei      = d_in[4];                 // [2, E]
    const void*  et      = d_in[5];                 // [E]

    const int N = in_sizes[0] / D;    // 50000
    const int E = in_sizes[4] / 2;    // 300000
    const int NP = N * RNUM;          // 400000 (dst,rel) pairs

    char* ws = (char*)d_ws;
    int* flag = (int*)ws;
    int* pp   = (int*)(ws + 256);     // NP+1
    int* cur  = pp + (NP + 1);        // NP
    int* bsum = cur + NP;             // 512
    int* esrc = bsum + 512;           // E
    size_t hoff = (256 + (size_t)(NP + 1 + NP + 512 + E) * 4 + 255) & ~(size_t)255;
    float* h1 = (float*)(ws + hoff);

    // --- build (dst,rel)-sorted CSR (identical work every call) ---
    detect_kernel<<<1, 256, 0, stream>>>((const int*)ei, flag);
    const int zn = 2 * NP + 513;                       // pp + cur + bsum contiguous
    zero_kernel<<<(zn + 255) / 256, 256, 0, stream>>>(pp, zn);
    const int eb = (E + 255) / 256;
    count_kernel<<<eb, 256, 0, stream>>>(ei, et, flag, pp, E, N);
    const int nb = (NP + 1023) / 1024;                 // 391
    scan_blocks_kernel<<<nb, 1024, 0, stream>>>(pp, bsum, NP);
    scan_sums_kernel<<<1, 512, 0, stream>>>(bsum, nb);
    scan_add_kernel<<<nb, 1024, 0, stream>>>(pp, bsum, NP, E);
    fill_kernel<<<eb, 256, 0, stream>>>(ei, et, flag, pp, cur, esrc, E, N);

    // --- 3 fused layers ---
    const int tiles = (N + BM - 1) / BM;               // 1563
    const float* hin = x;
    for (int l = 0; l < LAYERS; ++l) {
        float* hout = (l == 1) ? h1 : (float*)d_out;   // l0->d_out, l1->h1, l2->d_out
        const float* Wl = weights + (size_t)l * RNUM * D * D;
        const float* rl = roots + (size_t)l * D * D;
        const float* bl = biases + (size_t)l * D;
        if (l == LAYERS - 1)
            layer_kernel<1><<<tiles, 256, 0, stream>>>(hin, Wl, rl, bl, pp, esrc, hout, N);
        else
            layer_kernel<0><<<tiles, 256, 0, stream>>>(hin, Wl, rl, bl, pp, esrc, hout, N);
        hin = hout;
    }
}

// Round 7
// 1147.839 us; speedup vs baseline: 8.5130x; 5.1286x over previous
//
#include <hip/hip_runtime.h>
#include <hip/hip_bf16.h>
#include <cstdint>
#include <cstddef>

#define D 256
#define RNUM 8
#define LAYERS 3
#define SEGS 9            // root + 8 relations
#define KSTEPS 8          // 256 / 32
#define BM 32             // dst rows per block
#define AST 264           // A LDS row stride (bf16 elems)

typedef short bf16x8 __attribute__((ext_vector_type(8)));   // 8 bf16 (4 VGPRs)
typedef float f32x4  __attribute__((ext_vector_type(4)));   // MFMA accumulator

__device__ __forceinline__ unsigned short f2bf(float f) {
    union { float f; unsigned u; } x; x.f = f;
    unsigned r = x.u + 0x7fff + ((x.u >> 16) & 1);   // round-to-nearest-even
    return (unsigned short)(r >> 16);
}
__device__ __forceinline__ float bf2f(unsigned short h) {
    union { float f; unsigned u; } x; x.u = ((unsigned)h) << 16;
    return x.f;
}

// ---------------------------------------------------------------------------
// ws layout (bytes):
//   [0]     int flag
//   [256]   int pp[N*8+1]      counts -> exclusive scan (CSR over (dst,rel))
//   [..]    int cur[N*8], int bsum[512], int esrc[E]
//   [a1]    float h1[N*D]                                  51.2 MB
//   [a2]    ushort wblk[3*9*8*2*256*32]                    7.1 MB
// total ≈ 63 MB (same footprint as round 5, which ran without faulting)
// ---------------------------------------------------------------------------

__global__ void zero_kernel(int* __restrict__ p, int n) {
    int i = blockIdx.x * blockDim.x + threadIdx.x;
    if (i < n) p[i] = 0;
}

__global__ void detect_kernel(const int* __restrict__ ei32, int* __restrict__ flag) {
    __shared__ int allzero;
    if (threadIdx.x == 0) allzero = 1;
    __syncthreads();
    if (ei32[2 * threadIdx.x + 1] != 0) allzero = 0;  // benign race: all write 0
    __syncthreads();
    if (threadIdx.x == 0) flag[0] = allzero;
}

__device__ __forceinline__ void load_edge(const void* ei, const void* et, int flg,
                                          int e, int E, int N,
                                          int& s, int& d, int& r) {
    if (flg) {
        const long long* a = (const long long*)ei;
        const long long* b = (const long long*)et;
        s = (int)a[e]; d = (int)a[E + e]; r = (int)b[e];
    } else {
        const int* a = (const int*)ei;
        const int* b = (const int*)et;
        s = a[e]; d = a[E + e]; r = b[e];
    }
    if ((unsigned)s >= (unsigned)N) s = 0;
    if ((unsigned)d >= (unsigned)N) d = 0;
    if ((unsigned)r >= (unsigned)RNUM) r = 0;
}

__global__ void count_kernel(const void* __restrict__ ei, const void* __restrict__ et,
                             const int* __restrict__ flag, int* __restrict__ pp,
                             int E, int N) {
    int e = blockIdx.x * blockDim.x + threadIdx.x;
    if (e >= E) return;
    int s, d, r;
    load_edge(ei, et, flag[0], e, E, N, s, d, r);
    atomicAdd(&pp[d * RNUM + r], 1);
}

__global__ void scan_blocks_kernel(int* __restrict__ pp, int* __restrict__ bsum, int n) {
    __shared__ int sb[1024];
    const int t = threadIdx.x;
    const int i = blockIdx.x * 1024 + t;
    const int v = (i < n) ? pp[i] : 0;
    sb[t] = v;
    __syncthreads();
    for (int off = 1; off < 1024; off <<= 1) {
        int x = 0;
        if (t >= off) x = sb[t - off];
        __syncthreads();
        if (t >= off) sb[t] += x;
        __syncthreads();
    }
    if (i < n) pp[i] = sb[t] - v;
    if (t == 1023) bsum[blockIdx.x] = sb[t];
}

__global__ void scan_sums_kernel(int* __restrict__ bsum, int nb) {
    __shared__ int sb[512];
    const int t = threadIdx.x;
    const int v = (t < nb) ? bsum[t] : 0;
    sb[t] = v;
    __syncthreads();
    for (int off = 1; off < 512; off <<= 1) {
        int x = 0;
        if (t >= off) x = sb[t - off];
        __syncthreads();
        if (t >= off) sb[t] += x;
        __syncthreads();
    }
    if (t < nb) bsum[t] = sb[t] - v;
}

__global__ void scan_add_kernel(int* __restrict__ pp, const int* __restrict__ bsum,
                                int n, int E) {
    const int i = blockIdx.x * 1024 + threadIdx.x;
    if (i < n) pp[i] += bsum[blockIdx.x];
    if (i == 0) pp[n] = E;
}

__global__ void fill_kernel(const void* __restrict__ ei, const void* __restrict__ et,
                            const int* __restrict__ flag, const int* __restrict__ pp,
                            int* __restrict__ cur, int* __restrict__ esrc,
                            int E, int N) {
    int e = blockIdx.x * blockDim.x + threadIdx.x;
    if (e >= E) return;
    int s, d, r;
    load_edge(ei, et, flag[0], e, E, N, s, d, r);
    const int key = d * RNUM + r;
    const int pos = atomicAdd(&cur[key], 1);
    const int slot = pp[key] + pos;
    if ((unsigned)slot < (unsigned)E) esrc[slot] = s;
}

// ---------------------------------------------------------------------------
// W -> blocked bf16 hi/lo: wblk[l][seg][ks][hi/lo][col][kk] = B[ks*32+kk][col]
// ---------------------------------------------------------------------------
__global__ void wconvert_kernel(const float* __restrict__ weights,
                                const float* __restrict__ roots,
                                unsigned short* __restrict__ wblk) {
    const int total = LAYERS * SEGS * KSTEPS * 256 * 32;
    int idx = blockIdx.x * blockDim.x + threadIdx.x;
    if (idx >= total) return;
    const int kk  = idx & 31;
    const int col = (idx >> 5) & 255;
    const int ks  = (idx >> 13) & 7;
    const int sl  = idx >> 16;            // l*9 + seg
    const int seg = sl % SEGS, l = sl / SEGS;
    const int krow = ks * 32 + kk;
    float v;
    if (seg == 0)
        v = roots[((size_t)l * 256 + krow) * 256 + col];
    else
        v = weights[(((size_t)l * RNUM + (seg - 1)) * 256 + krow) * 256 + col];
    const unsigned short hi = f2bf(v);
    const unsigned short lo = f2bf(v - bf2f(hi));
    const size_t base = ((size_t)sl * KSTEPS + ks) * 16384;
    wblk[base + (size_t)col * 32 + kk] = hi;
    wblk[base + 8192 + (size_t)col * 32 + kk] = lo;
}

// ---------------------------------------------------------------------------
// Fused RGCN layer (MFMA, A and B both bf16 hi/lo split -> 3 products):
//   block = 32 dst rows x 256 cols; A staged in LDS per segment; B fragments
//   read directly from global (L2-resident, fragment-contiguous layout).
// ---------------------------------------------------------------------------
template <int ACT>  // 0 = relu, 1 = sigmoid
__global__ __launch_bounds__(256)
void layer_kernel(const float* __restrict__ hin,            // [N, D] fp32
                  const unsigned short* __restrict__ wl,    // this layer's wblk
                  const float* __restrict__ bias,           // [D]
                  const int* __restrict__ pp,               // [N*8+1]
                  const int* __restrict__ esrc,             // [E]
                  float* __restrict__ hout,                 // [N, D]
                  int N) {
    __shared__ unsigned short Ahi[BM * AST];   // 16,896 B
    __shared__ unsigned short Alo[BM * AST];   // 16,896 B

    const int tid = threadIdx.x;
    const int wv = tid >> 6;          // wave 0..3 -> cols [wv*64, wv*64+64)
    const int lane = tid & 63;
    const int lm = lane & 15;         // MFMA row/col lane index
    const int lq = lane >> 4;         // MFMA k-quad
    const int row_base = blockIdx.x * BM;

    f32x4 acc[2][4];                  // [row-tile][col-tile]
#pragma unroll
    for (int i = 0; i < 2; ++i)
#pragma unroll
        for (int j = 0; j < 4; ++j) acc[i][j] = (f32x4)0.f;

    for (int seg = 0; seg < SEGS; ++seg) {
        __syncthreads();   // all MFMA reads of Ahi/Alo from previous segment done

        // ---- stage A: wave wv owns rows wv, wv+4, ... (8 rows); 64 lanes = 256 k
        for (int m = wv; m < BM; m += 4) {
            int r = row_base + m;
            if (r >= N) r = N - 1;                 // tail clamp; store is masked
            float4 v;
            if (seg == 0) {
                v = *reinterpret_cast<const float4*>(hin + (size_t)r * D + lane * 4);
            } else {
                const int p = r * RNUM + (seg - 1);
                const int beg = pp[p], end = pp[p + 1];
                float sx = 0.f, sy = 0.f, sz = 0.f, sw = 0.f;
                for (int j = beg; j < end; ++j) {
                    const int s = esrc[j];
                    const float4 u = *reinterpret_cast<const float4*>(
                        hin + (size_t)s * D + lane * 4);
                    sx += u.x; sy += u.y; sz += u.z; sw += u.w;
                }
                v = make_float4(sx, sy, sz, sw);   // zeros when row has no edges
            }
            ushort4 hi4, lo4;
            hi4.x = f2bf(v.x); lo4.x = f2bf(v.x - bf2f(hi4.x));
            hi4.y = f2bf(v.y); lo4.y = f2bf(v.y - bf2f(hi4.y));
            hi4.z = f2bf(v.z); lo4.z = f2bf(v.z - bf2f(hi4.z));
            hi4.w = f2bf(v.w); lo4.w = f2bf(v.w - bf2f(hi4.w));
            *reinterpret_cast<ushort4*>(&Ahi[m * AST + lane * 4]) = hi4;
            *reinterpret_cast<ushort4*>(&Alo[m * AST + lane * 4]) = lo4;
        }
        __syncthreads();   // A tile visible

        const unsigned short* wseg = wl + (size_t)seg * KSTEPS * 16384;

        for (int ks = 0; ks < KSTEPS; ++ks) {
            // A fragments: lane holds A[m = lm][k = lq*8 + j]
            bf16x8 ah[2], al[2];
#pragma unroll
            for (int rt = 0; rt < 2; ++rt) {
                const int off = (rt * 16 + lm) * AST + ks * 32 + lq * 8;
                ah[rt] = *reinterpret_cast<const bf16x8*>(&Ahi[off]);
                al[rt] = *reinterpret_cast<const bf16x8*>(&Alo[off]);
            }
            // B fragments from global (L2): lane holds B[k = lq*8+j][col = lm]
            const unsigned short* wks = wseg + (size_t)ks * 16384;
            bf16x8 bh[4], bl[4];
#pragma unroll
            for (int ct = 0; ct < 4; ++ct) {
                const int c = wv * 64 + ct * 16 + lm;
                bh[ct] = *reinterpret_cast<const bf16x8*>(wks + c * 32 + lq * 8);
                bl[ct] = *reinterpret_cast<const bf16x8*>(wks + 8192 + c * 32 + lq * 8);
            }
#pragma unroll
            for (int rt = 0; rt < 2; ++rt)
#pragma unroll
                for (int ct = 0; ct < 4; ++ct) {
                    acc[rt][ct] = __builtin_amdgcn_mfma_f32_16x16x32_bf16(
                        ah[rt], bh[ct], acc[rt][ct], 0, 0, 0);
                    acc[rt][ct] = __builtin_amdgcn_mfma_f32_16x16x32_bf16(
                        ah[rt], bl[ct], acc[rt][ct], 0, 0, 0);
                    acc[rt][ct] = __builtin_amdgcn_mfma_f32_16x16x32_bf16(
                        al[rt], bh[ct], acc[rt][ct], 0, 0, 0);
                }
        }
    }

    // ---- epilogue: C/D layout col=lane&15, row=(lane>>4)*4+reg
#pragma unroll
    for (int ct = 0; ct < 4; ++ct) {
        const int col = wv * 64 + ct * 16 + lm;
        const float bb = bias[col];
#pragma unroll
        for (int rt = 0; rt < 2; ++rt) {
#pragma unroll
            for (int i = 0; i < 4; ++i) {
                const int row = row_base + rt * 16 + lq * 4 + i;
                if (row < N) {
                    float z = acc[rt][ct][i] + bb;
                    z = (ACT == 0) ? fmaxf(z, 0.f) : 1.f / (1.f + __expf(-z));
                    hout[(size_t)row * D + col] = z;
                }
            }
        }
    }
}

// ---------------------------------------------------------------------------
extern "C" void kernel_launch(void* const* d_in, const int* in_sizes, int n_in,
                              void* d_out, int out_size, void* d_ws, size_t ws_size,
                              hipStream_t stream) {
    const float* x       = (const float*)d_in[0];
    const float* weights = (const float*)d_in[1];   // [L, R, D, D]
    const float* roots   = (const float*)d_in[2];   // [L, D, D]
    const float* biases  = (const float*)d_in[3];   // [L, D]
    const void*  ei      = d_in[4];                 // [2, E]
    const void*  et      = d_in[5];                 // [E]

    const int N = in_sizes[0] / D;    // 50000
    const int E = in_sizes[4] / 2;    // 300000
    const int NP = N * RNUM;          // 400000

    char* ws = (char*)d_ws;
    int* flag = (int*)ws;
    int* pp   = (int*)(ws + 256);     // NP+1
    int* cur  = pp + (NP + 1);        // NP
    int* bsum = cur + NP;             // 512
    int* esrc = bsum + 512;           // E
    size_t hoff = (256 + (size_t)(NP + 1 + NP + 512 + E) * 4 + 255) & ~(size_t)255;
    float* h1 = (float*)(ws + hoff);
    unsigned short* wblk = (unsigned short*)(ws + hoff + (size_t)N * D * sizeof(float));

    // --- W conversion to MFMA-blocked bf16 hi/lo (all 3 layers) ---
    const int wtotal = LAYERS * SEGS * KSTEPS * 256 * 32;
    wconvert_kernel<<<(wtotal + 255) / 256, 256, 0, stream>>>(weights, roots, wblk);

    // --- build (dst,rel)-sorted CSR ---
    detect_kernel<<<1, 256, 0, stream>>>((const int*)ei, flag);
    const int zn = 2 * NP + 513;
    zero_kernel<<<(zn + 255) / 256, 256, 0, stream>>>(pp, zn);
    const int eb = (E + 255) / 256;
    count_kernel<<<eb, 256, 0, stream>>>(ei, et, flag, pp, E, N);
    const int nb = (NP + 1023) / 1024;
    scan_blocks_kernel<<<nb, 1024, 0, stream>>>(pp, bsum, NP);
    scan_sums_kernel<<<1, 512, 0, stream>>>(bsum, nb);
    scan_add_kernel<<<nb, 1024, 0, stream>>>(pp, bsum, NP, E);
    fill_kernel<<<eb, 256, 0, stream>>>(ei, et, flag, pp, cur, esrc, E, N);

    // --- 3 fused layers ---
    const int tiles = (N + BM - 1) / BM;   // 1563
    const size_t wlayer = (size_t)SEGS * KSTEPS * 16384;
    const float* hin = x;
    for (int l = 0; l < LAYERS; ++l) {
        float* hout = (l == 1) ? h1 : (float*)d_out;   // l0->d_out, l1->h1, l2->d_out
        const unsigned short* wlp = wblk + (size_t)l * wlayer;
        const float* bl = biases + (size_t)l * D;
        if (l == LAYERS - 1)
            layer_kernel<1><<<tiles, 256, 0, stream>>>(hin, wlp, bl, pp, esrc, hout, N);
        else
            layer_kernel<0><<<tiles, 256, 0, stream>>>(hin, wlp, bl, pp, esrc, hout, N);
        hin = hout;
    }
}